// Round 10
// baseline (113.473 us; speedup 1.0000x reference)
//
#include <hip/hip_runtime.h>

#define LOG2E 1.4426950408889634f

typedef __attribute__((ext_vector_type(8))) short bf16x8;
typedef __attribute__((ext_vector_type(4))) float f32x4;

union AF { unsigned u[4]; bf16x8 v; };

__device__ __forceinline__ unsigned short f2bf(float f) {
  unsigned int u = __float_as_uint(f);
  u = (u + 0x7fffu + ((u >> 16) & 1u)) >> 16;   // RNE, finite inputs only
  return (unsigned short)u;
}

// ---------------------------------------------------------------------------
// Kernel 1: f = X @ W^T + b  (fp32 SGEMM, 128x128 tile, 8x8/thread)
// Emits: ft (bf16, layout [b][n/16][h][c][n%16]) and s_src/s_dst ([b][h][n],
// f32, PRE-SCALED by log2(e) so k2 can use raw v_exp_f32).
// ---------------------------------------------------------------------------
__global__ __launch_bounds__(256) void gat_k1(
    const float* __restrict__ X, const float* __restrict__ W,
    const float* __restrict__ bias, const float* __restrict__ a,
    unsigned short* __restrict__ ft, float* __restrict__ ssrc,
    float* __restrict__ sdst)
{
  __shared__ float Xs[8][128];
  __shared__ float Ws[8][128];
  const int tid = threadIdx.x;
  const int tx = tid & 15, ty = tid >> 4;
  const int m0 = blockIdx.x * 128;
  const int c0 = blockIdx.y * 128;

  float acc[8][8];
#pragma unroll
  for (int r = 0; r < 8; ++r)
#pragma unroll
    for (int j = 0; j < 8; ++j) acc[r][j] = 0.f;

  const int lrow = tid >> 1;
  const int kk0 = (tid & 1) * 4;
  const float* Xp = X + (size_t)(m0 + lrow) * 256 + kk0;
  const float* Wp = W + (size_t)(c0 + lrow) * 256 + kk0;

  for (int kc = 0; kc < 256; kc += 8) {
    float4 xv = *(const float4*)(Xp + kc);
    float4 wv = *(const float4*)(Wp + kc);
    __syncthreads();
    Xs[kk0 + 0][lrow] = xv.x; Xs[kk0 + 1][lrow] = xv.y;
    Xs[kk0 + 2][lrow] = xv.z; Xs[kk0 + 3][lrow] = xv.w;
    Ws[kk0 + 0][lrow] = wv.x; Ws[kk0 + 1][lrow] = wv.y;
    Ws[kk0 + 2][lrow] = wv.z; Ws[kk0 + 3][lrow] = wv.w;
    __syncthreads();
#pragma unroll
    for (int kk = 0; kk < 8; ++kk) {
      float av[8], wv8[8];
#pragma unroll
      for (int r = 0; r < 8; ++r) av[r] = Xs[kk][ty * 8 + r];
#pragma unroll
      for (int j = 0; j < 8; ++j) wv8[j] = Ws[kk][tx * 8 + j];
#pragma unroll
      for (int r = 0; r < 8; ++r)
#pragma unroll
        for (int j = 0; j < 8; ++j) acc[r][j] = fmaf(av[r], wv8[j], acc[r][j]);
    }
  }

  const int b = m0 >> 11;
  const int nloc0 = (m0 & 2047) + ty * 8;
  const int cg0 = c0 + tx * 8;
  const int h = cg0 >> 6;
  const int cb = cg0 & 63;

  float bv[8], av_s[8], av_d[8];
#pragma unroll
  for (int j = 0; j < 8; ++j) {
    bv[j]   = bias[cg0 + j];
    av_s[j] = a[h * 128 + cb + j];
    av_d[j] = a[h * 128 + 64 + cb + j];
  }
#pragma unroll
  for (int r = 0; r < 8; ++r)
#pragma unroll
    for (int j = 0; j < 8; ++j) acc[r][j] += bv[j];

  const int jt = nloc0 >> 4;
  const int ni = nloc0 & 15;
#pragma unroll
  for (int j = 0; j < 8; ++j) {
    unsigned int u[4];
#pragma unroll
    for (int q = 0; q < 4; ++q) {
      unsigned int lo = f2bf(acc[2 * q + 0][j]);
      unsigned int hi = f2bf(acc[2 * q + 1][j]);
      u[q] = lo | (hi << 16);
    }
    size_t off = ((((size_t)b * 128 + jt) * 4 + h) * 64 + (cb + j)) * 16 + ni;
    *(uint4*)(ft + off) = make_uint4(u[0], u[1], u[2], u[3]);
  }

  float sp[8], dp[8];
#pragma unroll
  for (int r = 0; r < 8; ++r) {
    float s = 0.f, d = 0.f;
#pragma unroll
    for (int j = 0; j < 8; ++j) {
      s = fmaf(acc[r][j], av_s[j], s);
      d = fmaf(acc[r][j], av_d[j], d);
    }
    sp[r] = s; dp[r] = d;
  }
#pragma unroll
  for (int off = 1; off < 8; off <<= 1) {
#pragma unroll
    for (int r = 0; r < 8; ++r) {
      sp[r] += __shfl_xor(sp[r], off);
      dp[r] += __shfl_xor(dp[r], off);
    }
  }
  if ((tx & 7) == 0) {
    float* sb = ssrc + ((size_t)b * 4 + h) * 2048 + nloc0;
    float* db = sdst + ((size_t)b * 4 + h) * 2048 + nloc0;
#pragma unroll
    for (int r = 0; r < 8; ++r) { sb[r] = sp[r] * LOG2E; db[r] = dp[r] * LOG2E; }
  }
}

// ---------------------------------------------------------------------------
// Kernel 2: fused mask + leaky-relu + softmax + PV (bf16 MFMA 16x16x32)
// Grid 256 blocks (b = idx&7 XCD-pinned, itile = idx>>3, 64 i-rows) x
// 1024 thr = 16 waves = (head h 0..3, row-group rg 0..3, 16 rows each).
// Each wave covers ALL 2048 j (64 steps of 32): denominator complete
// per-wave (ones-MFMA acc4) -> epilogue has no combine at all.
// ft re-read/block amortized over 64 rows: 256 MB total (was 1 GB), and
// the 4 rg-waves of a head share fragments -> L1 reuse.
// adj staged in 8 windows of 256 j (double-buffered 2KB masks in LDS):
// loads issued before each window's 8 steps, packed after -> HBM overlap.
// ---------------------------------------------------------------------------
__global__ __launch_bounds__(1024, 4) void gat_k2(
    const int* __restrict__ adj, const unsigned short* __restrict__ ft,
    const float* __restrict__ ssrc, const float* __restrict__ sdst,
    float* __restrict__ out)
{
  __shared__ __align__(16) unsigned char lds[36928];  // sd 32KB | Awin [2][8][65] u32
  float* sd = (float*)lds;                            // [4][2048] f32
  unsigned* Awin = (unsigned*)(lds + 32768);          // [2][8][65] u32

  const int tid = threadIdx.x;
  const int b = blockIdx.x & 7;
  const int itile = blockIdx.x >> 3;     // 0..31
  const int i0 = itile * 64;
  const int wv = tid >> 6;
  const int h = wv >> 2;                 // head 0..3
  const int rg = wv & 3;                 // row-group 0..3
  const int lane = tid & 63;
  const int i_l = lane & 15;             // A-row within 16 / c within c-block
  const int kg = lane >> 4;              // k-group 0..3
  const int shamt = kg * 8;

  // ft base (bf16x8 units); step stride 1024 units (16 KB = 2 jt)
  const bf16x8* fp = (const bf16x8*)ft +
      ((((size_t)b * 128 + (kg >> 1)) * 4 + h) * 64 + i_l) * 2 + (kg & 1);

  bf16x8 A0, A1, A2, A3, B0, B1, B2, B3;
#define LDF(F0_, F1_, F2_, F3_)                                    \
  { F0_ = fp[0]; F1_ = fp[32]; F2_ = fp[64]; F3_ = fp[96]; fp += 1024; }

  // prologue ft prefetch: steps 0,1 (issued before any LDS work)
  LDF(A0, A1, A2, A3)
  LDF(B0, B1, B2, B3)

  // ---- stage s_dst (32 KB contiguous) ----
  {
    const float4* src = (const float4*)(sdst + (size_t)b * 4 * 2048);
    float4* dst = (float4*)sd;
    dst[tid]        = src[tid];
    dst[tid + 1024] = src[tid + 1024];
  }

  // ---- adj windowed staging setup: thread -> (row, 16-j group) ----
  const int arow = tid >> 4;             // 0..63
  const int ajg  = tid & 15;             // 0..15
  const int* abase = adj + (size_t)b * 4194304 +
                     (size_t)(i0 + arow) * 2048 + ajg * 16;

#define PACKW(bufbit, v0_, v1_, v2_, v3_)                          \
  {                                                                \
    int vv[16] = {v0_.x, v0_.y, v0_.z, v0_.w, v1_.x, v1_.y,        \
                  v1_.z, v1_.w, v2_.x, v2_.y, v2_.z, v2_.w,        \
                  v3_.x, v3_.y, v3_.z, v3_.w};                     \
    unsigned m_ = 0;                                               \
    _Pragma("unroll")                                              \
    for (int i = 0; i < 16; ++i) m_ |= (vv[i] ? 1u : 0u) << i;     \
    ((unsigned short*)Awin)[(((bufbit) * 8 + (ajg >> 1)) * 65 +    \
                             arow) * 2 + (ajg & 1)] = (unsigned short)m_; \
  }

  // window 0 -> buffer 0
  {
    const int4* ap = (const int4*)abase;
    int4 q0 = ap[0], q1 = ap[1], q2 = ap[2], q3 = ap[3];
    PACKW(0, q0, q1, q2, q3)
  }

  const float si = ssrc[((size_t)b * 4 + h) * 2048 + i0 + rg * 16 + i_l];
  const float* sdp = sd + h * 2048 + kg * 8;
  const unsigned* aw0 = Awin + rg * 16 + i_l;

  f32x4 acc0, acc1, acc2, acc3, acc4;
#pragma unroll
  for (int q = 0; q < 4; ++q) {
    acc0[q] = 0.f; acc1[q] = 0.f; acc2[q] = 0.f; acc3[q] = 0.f; acc4[q] = 0.f;
  }
  bf16x8 ones;
#pragma unroll
  for (int q = 0; q < 8; ++q) ones[q] = (short)0x3F80;  // bf16 1.0

  __syncthreads();

#define STEPX(jj_, F0_, F1_, F2_, F3_)                             \
  {                                                                \
    const unsigned mw_ = awb[(jj_) * 65];                          \
    float4 t0_ = *(const float4*)(sdp + (jj_) * 32);               \
    float4 t1_ = *(const float4*)(sdp + (jj_) * 32 + 4);           \
    const unsigned byte_ = (mw_ >> shamt) & 0xffu;                 \
    float tj_[8] = {t0_.x, t0_.y, t0_.z, t0_.w,                    \
                    t1_.x, t1_.y, t1_.z, t1_.w};                   \
    float e_[8];                                                   \
    _Pragma("unroll")                                              \
    for (int q = 0; q < 8; ++q) {                                  \
      float x_ = si + tj_[q];                                      \
      float y_ = fmaxf(x_, 0.2f * x_);                             \
      float ev_ = __builtin_amdgcn_exp2f(y_);                      \
      e_[q] = (byte_ & (1u << q)) ? ev_ : 0.f;                     \
    }                                                              \
    AF af_;                                                        \
    _Pragma("unroll")                                              \
    for (int q2 = 0; q2 < 4; ++q2) {                               \
      unsigned r_;                                                 \
      asm("v_cvt_pk_bf16_f32 %0, %1, %2"                           \
          : "=v"(r_) : "v"(e_[2 * q2]), "v"(e_[2 * q2 + 1]));      \
      af_.u[q2] = r_;                                              \
    }                                                              \
    acc0 = __builtin_amdgcn_mfma_f32_16x16x32_bf16(af_.v, F0_, acc0, 0, 0, 0); \
    acc1 = __builtin_amdgcn_mfma_f32_16x16x32_bf16(af_.v, F1_, acc1, 0, 0, 0); \
    acc2 = __builtin_amdgcn_mfma_f32_16x16x32_bf16(af_.v, F2_, acc2, 0, 0, 0); \
    acc3 = __builtin_amdgcn_mfma_f32_16x16x32_bf16(af_.v, F3_, acc3, 0, 0, 0); \
    acc4 = __builtin_amdgcn_mfma_f32_16x16x32_bf16(af_.v, ones, acc4, 0, 0, 0); \
  }

  for (int w = 0; w < 8; ++w) {
    // issue next window's adj loads early (HBM latency hides under 8 steps)
    int4 v0, v1, v2, v3;
    if (w < 7) {
      const int4* ap = (const int4*)(abase + (w + 1) * 256);
      v0 = ap[0]; v1 = ap[1]; v2 = ap[2]; v3 = ap[3];
    }
    const unsigned* awb = aw0 + (w & 1) * 520;
    // 8 steps, depth-2 ft rotation (prefetch overruns ft by <=32KB into
    // ssrc/sdst region on the last window -- in-bounds of d_ws, unused)
    STEPX(0, A0, A1, A2, A3) LDF(A0, A1, A2, A3)
    STEPX(1, B0, B1, B2, B3) LDF(B0, B1, B2, B3)
    STEPX(2, A0, A1, A2, A3) LDF(A0, A1, A2, A3)
    STEPX(3, B0, B1, B2, B3) LDF(B0, B1, B2, B3)
    STEPX(4, A0, A1, A2, A3) LDF(A0, A1, A2, A3)
    STEPX(5, B0, B1, B2, B3) LDF(B0, B1, B2, B3)
    STEPX(6, A0, A1, A2, A3) LDF(A0, A1, A2, A3)
    STEPX(7, B0, B1, B2, B3) LDF(B0, B1, B2, B3)
    sdp += 256;
    if (w < 7) PACKW((w + 1) & 1, v0, v1, v2, v3)
    __syncthreads();
  }
#undef STEPX
#undef LDF
#undef PACKW

  // ---- epilogue: acc4[r] = full row sum (all j) -> direct normalize/store ----
  float* ob = out + ((size_t)(b * 2048 + i0 + rg * 16)) * 256 + h * 64;
#pragma unroll
  for (int r = 0; r < 4; ++r) {
    const int row = kg * 4 + r;
    const float ri = 1.0f / acc4[r];
    ob[(size_t)row * 256 + 0  + i_l] = acc0[r] * ri;
    ob[(size_t)row * 256 + 16 + i_l] = acc1[r] * ri;
    ob[(size_t)row * 256 + 32 + i_l] = acc2[r] * ri;
    ob[(size_t)row * 256 + 48 + i_l] = acc3[r] * ri;
  }
}

// ---------------------------------------------------------------------------
extern "C" void kernel_launch(void* const* d_in, const int* in_sizes, int n_in,
                              void* d_out, int out_size, void* d_ws, size_t ws_size,
                              hipStream_t stream) {
  const float* X    = (const float*)d_in[0];   // (8,2048,256) f32
  const int*   adj  = (const int*)d_in[1];     // (8,2048,2048) i32
  const float* W    = (const float*)d_in[2];   // (256,256) f32
  const float* bias = (const float*)d_in[3];   // (256,) f32
  const float* a    = (const float*)d_in[4];   // (4,128) f32
  float* out = (float*)d_out;

  unsigned short* ft = (unsigned short*)d_ws;                    // 8 MB bf16
  float* ssrc = (float*)((char*)d_ws + 8388608);                 // 256 KB
  float* sdst = ssrc + 8 * 4 * 2048;                             // 256 KB

  gat_k1<<<dim3(128, 2, 1), 256, 0, stream>>>(X, W, bias, a, ft, ssrc, sdst);
  gat_k2<<<dim3(256, 1, 1), 1024, 0, stream>>>(adj, ft, ssrc, sdst, out);
}